// Round 4
// baseline (196.163 us; speedup 1.0000x reference)
//
#include <hip/hip_runtime.h>
#include <math.h>
#include <stdint.h>

// ---------------------------------------------------------------------------
// TransformerLayer (Swin-style) on MI355X. FP32 I/O; bf16 MFMA internals.
// B=2, H=W=128, C=128, NS=8 -> 64 windows x 256 tokens; HID=1024.
// R11: fused_ffn -> 2 independent blocks/CU (grid 512 x 64 rows, 512 thr,
//      72KB LDS). W1 single-buffered (32KB), W2 double (32KB), Gs single
//      (8KB). Two barrier domains per CU fill each other's load-drain
//      stalls (m114 cross-block overlap). Same MFMA partition as R10.
// ---------------------------------------------------------------------------

typedef unsigned short u16;
typedef __attribute__((ext_vector_type(8))) short bf16x8;   // 8 bf16 (4 VGPRs)
typedef __attribute__((ext_vector_type(4))) float f32x4;
typedef __attribute__((ext_vector_type(4))) short u16x4;
typedef __attribute__((ext_vector_type(2))) unsigned int u32x2;

__device__ __forceinline__ u16 f2b(float f) {
    unsigned int i = __float_as_uint(f);
    unsigned int r = (i + 0x7fffu + ((i >> 16) & 1u)) >> 16;
    return (u16)r;
}

// gelu via A-S 7.1.28 erf (|eps|<=5e-4): ONE transcendental (rcp).
__device__ __forceinline__ float gelu_e(float x) {
    float y = fabsf(x) * 0.70710678118f;
    float u = fmaf(y, fmaf(y, fmaf(y, fmaf(y, 0.078108f, 0.000972f),
                                   0.230389f), 0.278393f), 1.0f);
    u = u * u; u = u * u;
    float r = __builtin_amdgcn_rcpf(u);
    return fmaxf(x, 0.f) - 0.5f * fabsf(x) * r;
}

// 16B async global->LDS (m97-verified). LDS dest wave-uniform base + lane*16.
__device__ __forceinline__ void cp16(const void* g, void* l) {
    auto* gp = reinterpret_cast<const __attribute__((address_space(1))) unsigned int*>(
        reinterpret_cast<uintptr_t>(g));
    auto* lp = reinterpret_cast<__attribute__((address_space(3))) unsigned int*>(
        reinterpret_cast<uintptr_t>(l));
    __builtin_amdgcn_global_load_lds(gp, lp, 16, 0, 0);
}

// window row (b*16384 + win*256 + t) -> source-order row (b*16384 + h*128 + w)
__device__ __forceinline__ int win_map(int gm) {
    int b = gm >> 14, rr = gm & 16383;
    int win = rr >> 8, t = rr & 255;
    int wi = win >> 3, wj = win & 7, i = t >> 4, j = t & 15;
    int h = (wi * 16 + i + 8) & 127;
    int w = (wj * 16 + j + 8) & 127;
    return (b << 14) + h * 128 + w;
}

// ---------------------------------------------------------------------------
// Fused QKV: grid (256, 3). y=0: q=src@Wq, y=1: k=tgt@Wk (window layouts),
// y=2: v=tgt@Wv stored transposed per window. K=128 fully LDS-resident.
// ---------------------------------------------------------------------------
__global__ __launch_bounds__(256, 2)
void gemm_qkv(const u16* __restrict__ srcb, const u16* __restrict__ tgtb,
              const u16* __restrict__ Bt, u16* __restrict__ qw,
              u16* __restrict__ kw, u16* __restrict__ vwt)
{
    __shared__ __align__(16) u16 SMEM[32768];   // As[4][128][32] | Bs[4][128][32]
    u16* As = SMEM;
    u16* Bs = SMEM + 16384;
    u16* Ts = SMEM;                              // 128x136 epilogue overlay

    const int tid = threadIdx.x;
    const int w = tid >> 6, lane = tid & 63;
    const int lm = lane & 15, q = lane >> 4;
    const int wm = w >> 1, wn = w & 1;
    const int m0 = blockIdx.x * 128;
    const int y = blockIdx.y;
    const u16* Ab = (y == 0) ? srcb : tgtb;

#pragma unroll
    for (int s = 0; s < 4; ++s)
#pragma unroll
        for (int i = 0; i < 2; ++i) {
            int row = w * 32 + i * 16 + (lane >> 2);
            int kc = s * 32 + (lane & 3) * 8;
            cp16(Ab + (size_t)win_map(m0 + row) * 128 + kc,
                 (void*)(As + (s * 128 + w * 32 + i * 16) * 32));
            cp16(Bt + (size_t)(y * 128 + row) * 128 + kc,
                 (void*)(Bs + (s * 128 + w * 32 + i * 16) * 32));
        }
    __syncthreads();

    f32x4 acc[4][4] = {};
#pragma unroll
    for (int s = 0; s < 4; ++s) {
        bf16x8 af[4], bfr[4];
#pragma unroll
        for (int t = 0; t < 4; ++t)
            af[t] = *(const bf16x8*)(As + (s * 128 + wm * 64 + t * 16 + lm) * 32 + q * 8);
#pragma unroll
        for (int t = 0; t < 4; ++t)
            bfr[t] = *(const bf16x8*)(Bs + (s * 128 + wn * 64 + t * 16 + lm) * 32 + q * 8);
#pragma unroll
        for (int mt = 0; mt < 4; ++mt)
#pragma unroll
            for (int nt = 0; nt < 4; ++nt)
                acc[mt][nt] = __builtin_amdgcn_mfma_f32_16x16x32_bf16(
                    af[mt], bfr[nt], acc[mt][nt], 0, 0, 0);
    }

    __syncthreads();
#pragma unroll
    for (int mt = 0; mt < 4; ++mt)
#pragma unroll
        for (int nt = 0; nt < 4; ++nt)
#pragma unroll
            for (int r = 0; r < 4; ++r) {
                int rowl = wm * 64 + mt * 16 + q * 4 + r;
                int col = wn * 64 + nt * 16 + lm;
                int idx = (y == 2) ? col * 136 + rowl : rowl * 136 + col;
                Ts[idx] = f2b(acc[mt][nt][r]);
            }
    __syncthreads();
    const int c8 = (tid & 15) * 8;
#pragma unroll
    for (int i = 0; i < 8; ++i) {
        int rr = i * 16 + (tid >> 4);
        bf16x8 t = *(const bf16x8*)(Ts + rr * 136 + c8);
        if (y == 2) {
            int wix = m0 >> 8, tok0 = m0 & 255;   // vwT[(b*64+win)*128+ch][tok]
            *(bf16x8*)(vwt + (size_t)wix * 32768 + (size_t)rr * 256 + tok0 + c8) = t;
        } else {
            u16* Cv = (y == 0) ? qw : kw;
            *(bf16x8*)(Cv + (size_t)(m0 + rr) * 128 + c8) = t;
        }
    }
}

// ---------------------------------------------------------------------------
// Fused attention + msg-proj + LayerNorm, fully LDS-staged operands.
// One block = 64 Q rows of a window; grid 512. LDS: Ps 33.8KB + B32 32KB.
// ---------------------------------------------------------------------------
__global__ __launch_bounds__(256, 2)
void attn_msg(const u16* __restrict__ qw, const u16* __restrict__ kw,
              const u16* __restrict__ vt, const u16* __restrict__ wmt,
              const float* __restrict__ g, const float* __restrict__ bb,
              u16* __restrict__ msgb)
{
    __shared__ __align__(16) u16 Ps[64 * 264];   // P (stride 264); Q/Ot overlays
    __shared__ __align__(16) u16 B32[16384];     // 32KB staging buffer

    const int tid = threadIdx.x, w = tid >> 6, lane = tid & 63;
    const int lm = lane & 15, q = lane >> 4;
    const int l4r = lane >> 2, l4c = (lane & 3) * 8;
    const int bid = blockIdx.x;
    const int qc = bid & 3, win = (bid >> 2) & 63, b = bid >> 8;
    const int wi = win >> 3, wj = win & 7;
    const int q0 = qc * 64;
    const size_t wbase = (size_t)(b * 64 + win);
    const u16* kwb = kw + wbase * 256 * 128;
    const u16* qwb = qw + wbase * 256 * 128;
    const u16* vtb = vt + wbase * 128 * 256;

    // ---- stage Q (Ps overlay, [4 kt][64 row][32]) + K tok[0,128) ----
    u16* Qs = Ps;
#pragma unroll
    for (int i = 0; i < 4; ++i)
        cp16(qwb + (size_t)(q0 + w * 16 + l4r) * 128 + i * 32 + l4c,
             (void*)(Qs + (i * 64 + w * 16) * 32));
#pragma unroll
    for (int s = 0; s < 4; ++s)
#pragma unroll
        for (int i = 0; i < 2; ++i) {
            int tok = w * 32 + i * 16 + l4r;
            cp16(kwb + (size_t)tok * 128 + s * 32 + l4c,
                 (void*)(B32 + (s * 128 + w * 32 + i * 16) * 32));
        }
    __syncthreads();

    bf16x8 af[4];
#pragma unroll
    for (int kt = 0; kt < 4; ++kt)
        af[kt] = *(const bf16x8*)(Qs + (kt * 64 + w * 16 + lm) * 32 + q * 8);

    f32x4 s[16];
#pragma unroll
    for (int nt = 0; nt < 16; ++nt) { f32x4 z = {0.f, 0.f, 0.f, 0.f}; s[nt] = z; }
#pragma unroll
    for (int kt = 0; kt < 4; ++kt)
#pragma unroll
        for (int nt = 0; nt < 8; ++nt) {
            bf16x8 bf = *(const bf16x8*)(B32 + (kt * 128 + nt * 16 + lm) * 32 + q * 8);
            s[nt] = __builtin_amdgcn_mfma_f32_16x16x32_bf16(af[kt], bf, s[nt], 0, 0, 0);
        }
    __syncthreads();
    // ---- K tok[128,256) ----
#pragma unroll
    for (int ss = 0; ss < 4; ++ss)
#pragma unroll
        for (int i = 0; i < 2; ++i) {
            int tok = 128 + w * 32 + i * 16 + l4r;
            cp16(kwb + (size_t)tok * 128 + ss * 32 + l4c,
                 (void*)(B32 + (ss * 128 + w * 32 + i * 16) * 32));
        }
    __syncthreads();
#pragma unroll
    for (int kt = 0; kt < 4; ++kt)
#pragma unroll
        for (int nt = 8; nt < 16; ++nt) {
            bf16x8 bf = *(const bf16x8*)(B32 + (kt * 128 + (nt - 8) * 16 + lm) * 32 + q * 8);
            s[nt] = __builtin_amdgcn_mfma_f32_16x16x32_bf16(af[kt], bf, s[nt], 0, 0, 0);
        }
    __syncthreads();   // B32 reads done -> free for V

    // ---- issue V tok[0,128) load, then softmax (overlap) ----
#pragma unroll
    for (int tt = 0; tt < 4; ++tt)
#pragma unroll
        for (int i = 0; i < 2; ++i) {
            int ch = w * 32 + i * 16 + l4r;
            cp16(vtb + (size_t)ch * 256 + tt * 32 + l4c,
                 (void*)(B32 + (tt * 128 + w * 32 + i * 16) * 32));
        }

    // analytic Swin mask + softmax (regs), P -> Ps
    int idk[16];
#pragma unroll
    for (int nt = 0; nt < 16; ++nt) {
        int rh = (wi == 7) ? ((nt >= 8) ? 2 : 1) : 0;
        int rw = (wj == 7) ? ((lm >= 8) ? 2 : 1) : 0;
        idk[nt] = rh * 3 + rw;
    }
    const float scale = 0.08838834764831845f;
#pragma unroll
    for (int r = 0; r < 4; ++r) {
        int tq = q0 + w * 16 + q * 4 + r;
        int iq = tq >> 4, jq = tq & 15;
        int rhq = (wi == 7) ? ((iq >= 8) ? 2 : 1) : 0;
        int rwq = (wj == 7) ? ((jq >= 8) ? 2 : 1) : 0;
        int idq = rhq * 3 + rwq;
        float sv[16];
        float mx = -1e30f;
#pragma unroll
        for (int nt = 0; nt < 16; ++nt) {
            float x = s[nt][r] * scale + ((idq != idk[nt]) ? -100.f : 0.f);
            sv[nt] = x; mx = fmaxf(mx, x);
        }
        mx = fmaxf(mx, __shfl_xor(mx, 1));
        mx = fmaxf(mx, __shfl_xor(mx, 2));
        mx = fmaxf(mx, __shfl_xor(mx, 4));
        mx = fmaxf(mx, __shfl_xor(mx, 8));
        float sum = 0.f;
#pragma unroll
        for (int nt = 0; nt < 16; ++nt) { float e = __expf(sv[nt] - mx); sv[nt] = e; sum += e; }
        sum += __shfl_xor(sum, 1);
        sum += __shfl_xor(sum, 2);
        sum += __shfl_xor(sum, 4);
        sum += __shfl_xor(sum, 8);
        float inv = 1.0f / sum;
#pragma unroll
        for (int nt = 0; nt < 16; ++nt)
            Ps[(w * 16 + q * 4 + r) * 264 + nt * 16 + lm] = f2b(sv[nt] * inv);
    }
    __syncthreads();   // V0 loaded (barrier drains vmcnt) + P visible

    // ---- PV tok[0,128) ----
    f32x4 o[8];
#pragma unroll
    for (int nt = 0; nt < 8; ++nt) { f32x4 z = {0.f, 0.f, 0.f, 0.f}; o[nt] = z; }
#pragma unroll
    for (int tt = 0; tt < 4; ++tt) {
        bf16x8 pf = *(const bf16x8*)(Ps + (w * 16 + lm) * 264 + tt * 32 + q * 8);
#pragma unroll
        for (int nt = 0; nt < 8; ++nt) {
            bf16x8 vf = *(const bf16x8*)(B32 + (tt * 128 + nt * 16 + lm) * 32 + q * 8);
            o[nt] = __builtin_amdgcn_mfma_f32_16x16x32_bf16(pf, vf, o[nt], 0, 0, 0);
        }
    }
    __syncthreads();
    // ---- V tok[128,256) ----
#pragma unroll
    for (int tt = 0; tt < 4; ++tt)
#pragma unroll
        for (int i = 0; i < 2; ++i) {
            int ch = w * 32 + i * 16 + l4r;
            cp16(vtb + (size_t)ch * 256 + 128 + tt * 32 + l4c,
                 (void*)(B32 + (tt * 128 + w * 32 + i * 16) * 32));
        }
    __syncthreads();
#pragma unroll
    for (int tt = 4; tt < 8; ++tt) {
        bf16x8 pf = *(const bf16x8*)(Ps + (w * 16 + lm) * 264 + tt * 32 + q * 8);
#pragma unroll
        for (int nt = 0; nt < 8; ++nt) {
            bf16x8 vf = *(const bf16x8*)(B32 + ((tt - 4) * 128 + nt * 16 + lm) * 32 + q * 8);
            o[nt] = __builtin_amdgcn_mfma_f32_16x16x32_bf16(pf, vf, o[nt], 0, 0, 0);
        }
    }
    __syncthreads();   // V reads + P reads done

    // ---- issue Wm stage; write O -> Ot (Ps overlay, A-layout) ----
#pragma unroll
    for (int ss = 0; ss < 4; ++ss)
#pragma unroll
        for (int i = 0; i < 2; ++i) {
            int n = w * 32 + i * 16 + l4r;
            cp16(wmt + (size_t)n * 128 + ss * 32 + l4c,
                 (void*)(B32 + (ss * 128 + w * 32 + i * 16) * 32));
        }
    u16* Ot = Ps;   // [64][136]
#pragma unroll
    for (int r = 0; r < 4; ++r) {
        int rl = w * 16 + q * 4 + r;
#pragma unroll
        for (int nt = 0; nt < 8; ++nt)
            Ot[rl * 136 + nt * 16 + lm] = f2b(o[nt][r]);
    }
    __syncthreads();

    // ---- msg = O @ WmT^T (all-LDS) ----
    f32x4 macc[8];
#pragma unroll
    for (int n2 = 0; n2 < 8; ++n2) { f32x4 z = {0.f, 0.f, 0.f, 0.f}; macc[n2] = z; }
#pragma unroll
    for (int kt = 0; kt < 4; ++kt) {
        bf16x8 paf = *(const bf16x8*)(Ot + (w * 16 + lm) * 136 + kt * 32 + q * 8);
#pragma unroll
        for (int n2 = 0; n2 < 8; ++n2) {
            bf16x8 wf = *(const bf16x8*)(B32 + (kt * 128 + n2 * 16 + lm) * 32 + q * 8);
            macc[n2] = __builtin_amdgcn_mfma_f32_16x16x32_bf16(paf, wf, macc[n2], 0, 0, 0);
        }
    }

    // ---- row LN + store (source-order rows) ----
    float gv[8], bv[8];
#pragma unroll
    for (int n2 = 0; n2 < 8; ++n2) {
        int col = n2 * 16 + lm;
        gv[n2] = g[col]; bv[n2] = bb[col];
    }
#pragma unroll
    for (int r = 0; r < 4; ++r) {
        float s1 = 0.f, s2 = 0.f;
#pragma unroll
        for (int n2 = 0; n2 < 8; ++n2) {
            float v = macc[n2][r];
            s1 += v; s2 += v * v;
        }
        s1 += __shfl_xor(s1, 1); s2 += __shfl_xor(s2, 1);
        s1 += __shfl_xor(s1, 2); s2 += __shfl_xor(s2, 2);
        s1 += __shfl_xor(s1, 4); s2 += __shfl_xor(s2, 4);
        s1 += __shfl_xor(s1, 8); s2 += __shfl_xor(s2, 8);
        float mean = s1 * (1.f / 128.f);
        float var = fmaxf(s2 * (1.f / 128.f) - mean * mean, 0.f);
        float rs = rsqrtf(var + 1e-5f);
        int t = q0 + w * 16 + q * 4 + r;
        int ii = t >> 4, jj = t & 15;
        int h = (wi * 16 + ii + 8) & 127;
        int w2 = (wj * 16 + jj + 8) & 127;
        size_t orow = ((size_t)b * 16384 + h * 128 + w2) * 128;
#pragma unroll
        for (int n2 = 0; n2 < 8; ++n2)
            msgb[orow + n2 * 16 + lm] = f2b((macc[n2][r] - mean) * rs * gv[n2] + bv[n2]);
    }
}

// ---------------------------------------------------------------------------
// FUSED FFN R11: out = resid + LN(gelu(cat(src,msg)@W1)@W2).
// Grid 512 (64 rows/block), 512 thr (8 waves), 72KB LDS -> 2 blocks/CU.
// Two independent barrier domains per CU: one block's load-drain stall is
// covered by the other's compute. Per chunk (64 HID cols x 16):
//   ffn1(c) from W1s(single)+areg -> gelu -> Gs(single); barrier;
//   stage W1(c+1)->W1s + W2(c+1)->W2s[nb]; ffn2(c) from Gs+W2s[cb]; barrier.
// ---------------------------------------------------------------------------
__global__ __launch_bounds__(512, 4)
void fused_ffn(const u16* __restrict__ A0, const u16* __restrict__ A1,
               const u16* __restrict__ W1T, const u16* __restrict__ W2T,
               const float* __restrict__ g, const float* __restrict__ bb,
               const float* __restrict__ resid, float* __restrict__ outv)
{
    __shared__ __align__(16) u16 W1s[16384];    // [8 ks][64 hid][32] 32KB single
    __shared__ __align__(16) u16 W2s[16384];    // [2 buf][2 ks][128 col][32] 32KB
    __shared__ __align__(16) u16 Gs[4096];      // [64 tok][64 k] swizzled 8KB

    const int tid = threadIdx.x;
    const int w = tid >> 6, lane = tid & 63;    // w in 0..7
    const int lm = lane & 15, q = lane >> 4;
    const int l4r = lane >> 2, l4c = (lane & 3) * 8;
    const int wm = w >> 2, wn = w & 3;          // wm: tok-32 half, wn: hid16/col32
    const int m0 = blockIdx.x * 64;

    // staging mappings (8 waves):
    // W1: wave w = k-section w (32 k); 4 cp16 stage hid rows i*16+l4r.
    // W2: wave w: ks = w>>2 (32 k), col-group (w&3)*32; 2 cp16 rows i*16+l4r.
    const u16* w1p = W1T + (size_t)l4r * 256 + w * 32 + l4c;
    const u16* w2p = W2T + (size_t)((w & 3) * 32 + l4r) * 1024 + (w >> 2) * 32 + l4c;
    u16* const w1d = W1s + (w * 64) * 32;
    u16* const w2d0 = W2s + (((w >> 2) * 128 + (w & 3) * 32)) * 32;
    u16* const w2d1 = w2d0 + 8192;

    // ---- A -> regs (one-time): tokens wm*32+mt*16+lm over K=256 ----
    bf16x8 areg[2][8];
#pragma unroll
    for (int mt = 0; mt < 2; ++mt)
#pragma unroll
        for (int ks = 0; ks < 8; ++ks) {
            const u16* Ab = (ks < 4) ? A0 : A1;
            areg[mt][ks] = *(const bf16x8*)(
                Ab + (size_t)(m0 + wm * 32 + mt * 16 + lm) * 128 + (ks & 3) * 32 + q * 8);
        }

    // ---- prologue: stage W1(0) -> W1s, W2(0) -> buf0 ----
#pragma unroll
    for (int i = 0; i < 4; ++i)
        cp16(w1p + (size_t)(i * 16) * 256, w1d + (i * 16) * 32);
#pragma unroll
    for (int i = 0; i < 2; ++i)
        cp16(w2p + (size_t)(i * 16) * 1024, w2d0 + (i * 16) * 32);
    w1p += 16384; w2p += 64;
    __syncthreads();                              // W(0) landed

    f32x4 acc2[2][2] = {};                        // 32x32 out tile per wave
#pragma unroll 2
    for (int c = 0; c < 16; ++c) {
        const int cb = c & 1, nb = cb ^ 1;

        // ---- ffn1(c): W1s + areg -> gelu -> Gs ----
        {
            f32x4 acc1[2] = {};
#pragma unroll
            for (int ks = 0; ks < 8; ++ks) {
                bf16x8 w1f = *(const bf16x8*)(W1s + (ks * 64 + wn * 16 + lm) * 32 + q * 8);
#pragma unroll
                for (int mt = 0; mt < 2; ++mt)
                    acc1[mt] = __builtin_amdgcn_mfma_f32_16x16x32_bf16(
                        w1f, areg[mt][ks], acc1[mt], 0, 0, 0);
            }
#pragma unroll
            for (int mt = 0; mt < 2; ++mt) {
                float g0 = gelu_e(acc1[mt][0]), g1 = gelu_e(acc1[mt][1]);
                float g2 = gelu_e(acc1[mt][2]), g3 = gelu_e(acc1[mt][3]);
                unsigned p0, p1;
                asm("v_cvt_pk_bf16_f32 %0, %1, %2" : "=v"(p0) : "v"(g0), "v"(g1));
                asm("v_cvt_pk_bf16_f32 %0, %1, %2" : "=v"(p1) : "v"(g2), "v"(g3));
                int tok = wm * 32 + mt * 16 + lm;
                int slot = (wn * 2 + (q >> 1)) ^ (tok & 7);
                u32x2 pk; pk[0] = p0; pk[1] = p1;
                *(u32x2*)(Gs + tok * 64 + slot * 8 + (q & 1) * 4) = pk;
            }
        }
        __syncthreads();   // Gs visible; all W1s(c) reads done -> W1s free

        // ---- stage W1(c+1) -> W1s, W2(c+1) -> buf[nb] (lands by next bar) ----
        if (c + 1 < 16) {
#pragma unroll
            for (int i = 0; i < 4; ++i)
                cp16(w1p + (size_t)(i * 16) * 256, w1d + (i * 16) * 32);
            u16* d = nb ? w2d1 : w2d0;
#pragma unroll
            for (int i = 0; i < 2; ++i)
                cp16(w2p + (size_t)(i * 16) * 1024, d + (i * 16) * 32);
        }
        w1p += 16384; w2p += 64;

        // ---- ffn2(c): Gs + W2s[cb] -> acc2 ----
        {
            const u16* W2c = W2s + cb * 8192;
#pragma unroll
            for (int ks = 0; ks < 2; ++ks) {
                bf16x8 pa[2], wf[2];
#pragma unroll
                for (int mt = 0; mt < 2; ++mt) {
                    int tok = wm * 32 + mt * 16 + lm;
                    pa[mt] = *(const bf16x8*)(Gs + tok * 64 + (((ks * 4 + q) ^ (tok & 7)) * 8));
                }
#pragma unroll
                for (int nt = 0; nt < 2; ++nt)
                    wf[nt] = *(const bf16x8*)(W2c + (ks * 128 + wn * 32 + nt * 16 + lm) * 32 + q * 8);
#pragma unroll
                for (int mt = 0; mt < 2; ++mt)
#pragma unroll
                    for (int nt = 0; nt < 2; ++nt)
                        acc2[mt][nt] = __builtin_amdgcn_mfma_f32_16x16x32_bf16(
                            pa[mt], wf[nt], acc2[mt][nt], 0, 0, 0);
            }
        }
        __syncthreads();   // drains vmcnt (W(c+1) landed); Gs reads done
    }

    // ---- LN + residual epilogue (stats exchange overlaid on Gs) ----
    float* stats = (float*)Gs;                   // [64][8] = 2KB
#pragma unroll
    for (int mt = 0; mt < 2; ++mt)
#pragma unroll
        for (int r = 0; r < 4; ++r) {
            float s1 = 0.f, s2 = 0.f;
#pragma unroll
            for (int nt = 0; nt < 2; ++nt) {
                float v = acc2[mt][nt][r];
                s1 += v; s2 += v * v;
            }
            s1 += __shfl_xor(s1, 1); s2 += __shfl_xor(s2, 1);
            s1 += __shfl_xor(s1, 2); s2 += __shfl_xor(s2, 2);
            s1 += __shfl_xor(s1, 4); s2 += __shfl_xor(s2, 4);
            s1 += __shfl_xor(s1, 8); s2 += __shfl_xor(s2, 8);
            if (lm == 0) {
                int row = wm * 32 + mt * 16 + q * 4 + r;
                stats[row * 8 + wn * 2] = s1;
                stats[row * 8 + wn * 2 + 1] = s2;
            }
        }
    __syncthreads();

    float gv[2], bv[2];
#pragma unroll
    for (int nt = 0; nt < 2; ++nt) {
        int col = wn * 32 + nt * 16 + lm;
        gv[nt] = g[col]; bv[nt] = bb[col];
    }
#pragma unroll
    for (int mt = 0; mt < 2; ++mt)
#pragma unroll
        for (int r = 0; r < 4; ++r) {
            int row = wm * 32 + mt * 16 + q * 4 + r;
            f32x4 st0 = *(const f32x4*)(stats + row * 8);
            f32x4 st1 = *(const f32x4*)(stats + row * 8 + 4);
            float s1 = st0[0] + st0[2] + st1[0] + st1[2];
            float s2 = st0[1] + st0[3] + st1[1] + st1[3];
            float mean = s1 * (1.f / 128.f);
            float var = fmaxf(s2 * (1.f / 128.f) - mean * mean, 0.f);
            float rs = rsqrtf(var + 1e-5f);
#pragma unroll
            for (int nt = 0; nt < 2; ++nt) {
                int col = wn * 32 + nt * 16 + lm;
                size_t gi = (size_t)(m0 + row) * 128 + col;
                outv[gi] = (acc2[mt][nt][r] - mean) * rs * gv[nt] + bv[nt] + resid[gi];
            }
        }
}

// ---------------------------------------------------------------------------
// Prep (merged): weight transposes write-coalesced; fp32->bf16 act cast.
// ---------------------------------------------------------------------------
__global__ void prep_all(const float* __restrict__ Wq, const float* __restrict__ Wk,
                         const float* __restrict__ Wv, const float* __restrict__ Wm,
                         const float* __restrict__ W1, const float* __restrict__ W2,
                         const float* __restrict__ src, const float* __restrict__ tgt,
                         u16* __restrict__ ws, u16* __restrict__ srcb,
                         u16* __restrict__ tgtb)
{
    int bx = blockIdx.x;
    if (bx < 1792) {
        int idx = bx * 256 + threadIdx.x;
        if (idx < 65536) {                       // Wq,Wk,Wv,Wm: 128x128
            int m = idx >> 14, e = idx & 16383;
            const float* sp = (m == 0) ? Wq : (m == 1) ? Wk : (m == 2) ? Wv : Wm;
            int n = e >> 7, k = e & 127;
            ws[m * 16384 + n * 128 + k] = f2b(sp[k * 128 + n]);
        } else if (idx < 327680) {               // W1 (256,1024) -> (1024,256)
            int e = idx - 65536;
            int n = e >> 8, k = e & 255;
            ws[65536 + n * 256 + k] = f2b(W1[k * 1024 + n]);
        } else {                                  // W2 (1024,128) -> (128,1024)
            int e = idx - 327680;
            int n = e >> 10, k = e & 1023;
            ws[327680 + n * 1024 + k] = f2b(W2[k * 128 + n]);
        }
    } else {
        int idx = (bx - 1792) * 256 + threadIdx.x;   // 0..2097151
        const float* s; u16* d; int i;
        if (idx < 1048576) { s = src; d = srcb; i = idx * 4; }
        else               { s = tgt; d = tgtb; i = (idx - 1048576) * 4; }
        f32x4 v = *(const f32x4*)(s + i);
        u16x4 o; o[0] = f2b(v[0]); o[1] = f2b(v[1]); o[2] = f2b(v[2]); o[3] = f2b(v[3]);
        *(u16x4*)(d + i) = o;
    }
}

// ---------------------------------------------------------------------------
// Workspace layout (u16 element offsets)
// ---------------------------------------------------------------------------
#define OFF_WQT  0u            // concat [WqT;WkT;WvT] 3x(128x128)
#define OFF_WMT  49152u
#define OFF_W1T  65536u
#define OFF_W2T  327680u
#define OFF_SRCB 458752u
#define OFF_TGTB 4653056u
#define OFF_QW   8847360u
#define OFF_KW   13041664u
#define OFF_VWT  17235968u
#define OFF_MSGB 21430272u     // bf16 msg, source-order; ends 25624576

extern "C" void kernel_launch(void* const* d_in, const int* in_sizes, int n_in,
                              void* d_out, int out_size, void* d_ws, size_t ws_size,
                              hipStream_t stream)
{
    (void)in_sizes; (void)n_in; (void)out_size; (void)ws_size;
    const float* source = (const float*)d_in[0];
    const float* target = (const float*)d_in[1];
    const float* Wq = (const float*)d_in[2];
    const float* Wk = (const float*)d_in[3];
    const float* Wv = (const float*)d_in[4];
    const float* Wm = (const float*)d_in[5];
    const float* g1 = (const float*)d_in[6];
    const float* b1 = (const float*)d_in[7];
    const float* W1 = (const float*)d_in[8];
    const float* W2 = (const float*)d_in[9];
    const float* g2 = (const float*)d_in[10];
    const float* b2 = (const float*)d_in[11];
    u16* ws = (u16*)d_ws;
    float* out = (float*)d_out;

    prep_all<<<9984, 256, 0, stream>>>(Wq, Wk, Wv, Wm, W1, W2, source, target,
                                       ws, ws + OFF_SRCB, ws + OFF_TGTB);
    gemm_qkv<<<dim3(256, 3), 256, 0, stream>>>(
        ws + OFF_SRCB, ws + OFF_TGTB, ws + OFF_WQT,
        ws + OFF_QW, ws + OFF_KW, ws + OFF_VWT);
    attn_msg<<<512, 256, 0, stream>>>(
        ws + OFF_QW, ws + OFF_KW, ws + OFF_VWT, ws + OFF_WMT, g1, b1,
        ws + OFF_MSGB);
    fused_ffn<<<512, 512, 0, stream>>>(
        ws + OFF_SRCB, ws + OFF_MSGB, ws + OFF_W1T, ws + OFF_W2T,
        g2, b2, source, out);
}

// Round 5
// 188.695 us; speedup vs baseline: 1.0396x; 1.0396x over previous
//
#include <hip/hip_runtime.h>
#include <math.h>
#include <stdint.h>

// ---------------------------------------------------------------------------
// TransformerLayer (Swin-style) on MI355X. FP32 I/O; bf16 MFMA internals.
// B=2, H=W=128, C=128, NS=8 -> 64 windows x 256 tokens; HID=1024.
// R12: fused_ffn frozen (3 structural nulls -> co-design problem, not a
//      one-lever fix). Target the unprofiled 146us instead:
//      - gemm_qkv: A frags global->reg direct; LDS 64->34.8KB (B + epilogue
//        only); 3 blocks/CU; stage drain halved.
//      - attn_msg: XCD-affinity blockIdx remap (window's 4 q-chunks 128
//        apart = same XCD) -> K/V/Wm stage drains hit local L2, not L3.
// ---------------------------------------------------------------------------

typedef unsigned short u16;
typedef __attribute__((ext_vector_type(8))) short bf16x8;   // 8 bf16 (4 VGPRs)
typedef __attribute__((ext_vector_type(4))) float f32x4;
typedef __attribute__((ext_vector_type(4))) short u16x4;
typedef __attribute__((ext_vector_type(2))) unsigned int u32x2;

__device__ __forceinline__ u16 f2b(float f) {
    unsigned int i = __float_as_uint(f);
    unsigned int r = (i + 0x7fffu + ((i >> 16) & 1u)) >> 16;
    return (u16)r;
}

// gelu via A-S 7.1.28 erf (|eps|<=5e-4): ONE transcendental (rcp).
__device__ __forceinline__ float gelu_e(float x) {
    float y = fabsf(x) * 0.70710678118f;
    float u = fmaf(y, fmaf(y, fmaf(y, fmaf(y, 0.078108f, 0.000972f),
                                   0.230389f), 0.278393f), 1.0f);
    u = u * u; u = u * u;
    float r = __builtin_amdgcn_rcpf(u);
    return fmaxf(x, 0.f) - 0.5f * fabsf(x) * r;
}

// 16B async global->LDS (m97-verified). LDS dest wave-uniform base + lane*16.
__device__ __forceinline__ void cp16(const void* g, void* l) {
    auto* gp = reinterpret_cast<const __attribute__((address_space(1))) unsigned int*>(
        reinterpret_cast<uintptr_t>(g));
    auto* lp = reinterpret_cast<__attribute__((address_space(3))) unsigned int*>(
        reinterpret_cast<uintptr_t>(l));
    __builtin_amdgcn_global_load_lds(gp, lp, 16, 0, 0);
}

// window row (b*16384 + win*256 + t) -> source-order row (b*16384 + h*128 + w)
__device__ __forceinline__ int win_map(int gm) {
    int b = gm >> 14, rr = gm & 16383;
    int win = rr >> 8, t = rr & 255;
    int wi = win >> 3, wj = win & 7, i = t >> 4, j = t & 15;
    int h = (wi * 16 + i + 8) & 127;
    int w = (wj * 16 + j + 8) & 127;
    return (b << 14) + h * 128 + w;
}

// ---------------------------------------------------------------------------
// Fused QKV R12: grid (256, 3). A-fragments loaded global->reg directly
// (each A element read exactly once per block; 64B sectors fully consumed
// by 4-lane groups). LDS holds only B (32KB) + 34.8KB epilogue overlay ->
// 3 blocks/CU. y=0: q=src@Wq, y=1: k=tgt@Wk, y=2: v stored transposed.
// ---------------------------------------------------------------------------
__global__ __launch_bounds__(256, 3)
void gemm_qkv(const u16* __restrict__ srcb, const u16* __restrict__ tgtb,
              const u16* __restrict__ Bt, u16* __restrict__ qw,
              u16* __restrict__ kw, u16* __restrict__ vwt)
{
    __shared__ __align__(16) u16 SMEM[17408];   // Bs[4][128][32] | Ts 128x136
    u16* Bs = SMEM;
    u16* Ts = SMEM;

    const int tid = threadIdx.x;
    const int w = tid >> 6, lane = tid & 63;
    const int lm = lane & 15, q = lane >> 4;
    const int wm = w >> 1, wn = w & 1;
    const int m0 = blockIdx.x * 128;
    const int y = blockIdx.y;
    const u16* Ab = (y == 0) ? srcb : tgtb;

    // ---- stage B (32KB) -> LDS ----
#pragma unroll
    for (int s = 0; s < 4; ++s)
#pragma unroll
        for (int i = 0; i < 2; ++i) {
            int row = w * 32 + i * 16 + (lane >> 2);
            int kc = s * 32 + (lane & 3) * 8;
            cp16(Bt + (size_t)(y * 128 + row) * 128 + kc,
                 (void*)(Bs + (s * 128 + w * 32 + i * 16) * 32));
        }

    // ---- A fragments: global -> registers (issued before barrier) ----
    bf16x8 af[4][4];
#pragma unroll
    for (int t = 0; t < 4; ++t) {
        int row = win_map(m0 + wm * 64 + t * 16 + lm);
#pragma unroll
        for (int s = 0; s < 4; ++s)
            af[t][s] = *(const bf16x8*)(Ab + (size_t)row * 128 + s * 32 + q * 8);
    }
    __syncthreads();   // B landed (also drains af loads)

    f32x4 acc[4][4] = {};
#pragma unroll
    for (int s = 0; s < 4; ++s) {
        bf16x8 bfr[4];
#pragma unroll
        for (int t = 0; t < 4; ++t)
            bfr[t] = *(const bf16x8*)(Bs + (s * 128 + wn * 64 + t * 16 + lm) * 32 + q * 8);
#pragma unroll
        for (int mt = 0; mt < 4; ++mt)
#pragma unroll
            for (int nt = 0; nt < 4; ++nt)
                acc[mt][nt] = __builtin_amdgcn_mfma_f32_16x16x32_bf16(
                    af[mt][s], bfr[nt], acc[mt][nt], 0, 0, 0);
    }

    __syncthreads();
#pragma unroll
    for (int mt = 0; mt < 4; ++mt)
#pragma unroll
        for (int nt = 0; nt < 4; ++nt)
#pragma unroll
            for (int r = 0; r < 4; ++r) {
                int rowl = wm * 64 + mt * 16 + q * 4 + r;
                int col = wn * 64 + nt * 16 + lm;
                int idx = (y == 2) ? col * 136 + rowl : rowl * 136 + col;
                Ts[idx] = f2b(acc[mt][nt][r]);
            }
    __syncthreads();
    const int c8 = (tid & 15) * 8;
#pragma unroll
    for (int i = 0; i < 8; ++i) {
        int rr = i * 16 + (tid >> 4);
        bf16x8 t = *(const bf16x8*)(Ts + rr * 136 + c8);
        if (y == 2) {
            int wix = m0 >> 8, tok0 = m0 & 255;   // vwT[(b*64+win)*128+ch][tok]
            *(bf16x8*)(vwt + (size_t)wix * 32768 + (size_t)rr * 256 + tok0 + c8) = t;
        } else {
            u16* Cv = (y == 0) ? qw : kw;
            *(bf16x8*)(Cv + (size_t)(m0 + rr) * 128 + c8) = t;
        }
    }
}

// ---------------------------------------------------------------------------
// Fused attention + msg-proj + LayerNorm, fully LDS-staged operands.
// One block = 64 Q rows of a window; grid 512. LDS: Ps 33.8KB + B32 32KB.
// R12: blockIdx remap -> a window's 4 q-chunk blocks are 128 apart
// (128 % 8 == 0 -> same XCD): K/V/Wm stages hit local L2 after 1st touch.
// ---------------------------------------------------------------------------
__global__ __launch_bounds__(256, 2)
void attn_msg(const u16* __restrict__ qw, const u16* __restrict__ kw,
              const u16* __restrict__ vt, const u16* __restrict__ wmt,
              const float* __restrict__ g, const float* __restrict__ bb,
              u16* __restrict__ msgb)
{
    __shared__ __align__(16) u16 Ps[64 * 264];   // P (stride 264); Q/Ot overlays
    __shared__ __align__(16) u16 B32[16384];     // 32KB staging buffer

    const int tid = threadIdx.x, w = tid >> 6, lane = tid & 63;
    const int lm = lane & 15, q = lane >> 4;
    const int l4r = lane >> 2, l4c = (lane & 3) * 8;
    const int bid = blockIdx.x;
    const int qc = bid >> 7;                     // XCD-affinity remap (R12)
    const int gwin = bid & 127;
    const int win = gwin & 63, b = gwin >> 6;
    const int wi = win >> 3, wj = win & 7;
    const int q0 = qc * 64;
    const size_t wbase = (size_t)(b * 64 + win);
    const u16* kwb = kw + wbase * 256 * 128;
    const u16* qwb = qw + wbase * 256 * 128;
    const u16* vtb = vt + wbase * 128 * 256;

    // ---- stage Q (Ps overlay, [4 kt][64 row][32]) + K tok[0,128) ----
    u16* Qs = Ps;
#pragma unroll
    for (int i = 0; i < 4; ++i)
        cp16(qwb + (size_t)(q0 + w * 16 + l4r) * 128 + i * 32 + l4c,
             (void*)(Qs + (i * 64 + w * 16) * 32));
#pragma unroll
    for (int s = 0; s < 4; ++s)
#pragma unroll
        for (int i = 0; i < 2; ++i) {
            int tok = w * 32 + i * 16 + l4r;
            cp16(kwb + (size_t)tok * 128 + s * 32 + l4c,
                 (void*)(B32 + (s * 128 + w * 32 + i * 16) * 32));
        }
    __syncthreads();

    bf16x8 af[4];
#pragma unroll
    for (int kt = 0; kt < 4; ++kt)
        af[kt] = *(const bf16x8*)(Qs + (kt * 64 + w * 16 + lm) * 32 + q * 8);

    f32x4 s[16];
#pragma unroll
    for (int nt = 0; nt < 16; ++nt) { f32x4 z = {0.f, 0.f, 0.f, 0.f}; s[nt] = z; }
#pragma unroll
    for (int kt = 0; kt < 4; ++kt)
#pragma unroll
        for (int nt = 0; nt < 8; ++nt) {
            bf16x8 bf = *(const bf16x8*)(B32 + (kt * 128 + nt * 16 + lm) * 32 + q * 8);
            s[nt] = __builtin_amdgcn_mfma_f32_16x16x32_bf16(af[kt], bf, s[nt], 0, 0, 0);
        }
    __syncthreads();
    // ---- K tok[128,256) ----
#pragma unroll
    for (int ss = 0; ss < 4; ++ss)
#pragma unroll
        for (int i = 0; i < 2; ++i) {
            int tok = 128 + w * 32 + i * 16 + l4r;
            cp16(kwb + (size_t)tok * 128 + ss * 32 + l4c,
                 (void*)(B32 + (ss * 128 + w * 32 + i * 16) * 32));
        }
    __syncthreads();
#pragma unroll
    for (int kt = 0; kt < 4; ++kt)
#pragma unroll
        for (int nt = 8; nt < 16; ++nt) {
            bf16x8 bf = *(const bf16x8*)(B32 + (kt * 128 + (nt - 8) * 16 + lm) * 32 + q * 8);
            s[nt] = __builtin_amdgcn_mfma_f32_16x16x32_bf16(af[kt], bf, s[nt], 0, 0, 0);
        }
    __syncthreads();   // B32 reads done -> free for V

    // ---- issue V tok[0,128) load, then softmax (overlap) ----
#pragma unroll
    for (int tt = 0; tt < 4; ++tt)
#pragma unroll
        for (int i = 0; i < 2; ++i) {
            int ch = w * 32 + i * 16 + l4r;
            cp16(vtb + (size_t)ch * 256 + tt * 32 + l4c,
                 (void*)(B32 + (tt * 128 + w * 32 + i * 16) * 32));
        }

    // analytic Swin mask + softmax (regs), P -> Ps
    int idk[16];
#pragma unroll
    for (int nt = 0; nt < 16; ++nt) {
        int rh = (wi == 7) ? ((nt >= 8) ? 2 : 1) : 0;
        int rw = (wj == 7) ? ((lm >= 8) ? 2 : 1) : 0;
        idk[nt] = rh * 3 + rw;
    }
    const float scale = 0.08838834764831845f;
#pragma unroll
    for (int r = 0; r < 4; ++r) {
        int tq = q0 + w * 16 + q * 4 + r;
        int iq = tq >> 4, jq = tq & 15;
        int rhq = (wi == 7) ? ((iq >= 8) ? 2 : 1) : 0;
        int rwq = (wj == 7) ? ((jq >= 8) ? 2 : 1) : 0;
        int idq = rhq * 3 + rwq;
        float sv[16];
        float mx = -1e30f;
#pragma unroll
        for (int nt = 0; nt < 16; ++nt) {
            float x = s[nt][r] * scale + ((idq != idk[nt]) ? -100.f : 0.f);
            sv[nt] = x; mx = fmaxf(mx, x);
        }
        mx = fmaxf(mx, __shfl_xor(mx, 1));
        mx = fmaxf(mx, __shfl_xor(mx, 2));
        mx = fmaxf(mx, __shfl_xor(mx, 4));
        mx = fmaxf(mx, __shfl_xor(mx, 8));
        float sum = 0.f;
#pragma unroll
        for (int nt = 0; nt < 16; ++nt) { float e = __expf(sv[nt] - mx); sv[nt] = e; sum += e; }
        sum += __shfl_xor(sum, 1);
        sum += __shfl_xor(sum, 2);
        sum += __shfl_xor(sum, 4);
        sum += __shfl_xor(sum, 8);
        float inv = 1.0f / sum;
#pragma unroll
        for (int nt = 0; nt < 16; ++nt)
            Ps[(w * 16 + q * 4 + r) * 264 + nt * 16 + lm] = f2b(sv[nt] * inv);
    }
    __syncthreads();   // V0 loaded (barrier drains vmcnt) + P visible

    // ---- PV tok[0,128) ----
    f32x4 o[8];
#pragma unroll
    for (int nt = 0; nt < 8; ++nt) { f32x4 z = {0.f, 0.f, 0.f, 0.f}; o[nt] = z; }
#pragma unroll
    for (int tt = 0; tt < 4; ++tt) {
        bf16x8 pf = *(const bf16x8*)(Ps + (w * 16 + lm) * 264 + tt * 32 + q * 8);
#pragma unroll
        for (int nt = 0; nt < 8; ++nt) {
            bf16x8 vf = *(const bf16x8*)(B32 + (tt * 128 + nt * 16 + lm) * 32 + q * 8);
            o[nt] = __builtin_amdgcn_mfma_f32_16x16x32_bf16(pf, vf, o[nt], 0, 0, 0);
        }
    }
    __syncthreads();
    // ---- V tok[128,256) ----
#pragma unroll
    for (int tt = 0; tt < 4; ++tt)
#pragma unroll
        for (int i = 0; i < 2; ++i) {
            int ch = w * 32 + i * 16 + l4r;
            cp16(vtb + (size_t)ch * 256 + 128 + tt * 32 + l4c,
                 (void*)(B32 + (tt * 128 + w * 32 + i * 16) * 32));
        }
    __syncthreads();
#pragma unroll
    for (int tt = 4; tt < 8; ++tt) {
        bf16x8 pf = *(const bf16x8*)(Ps + (w * 16 + lm) * 264 + tt * 32 + q * 8);
#pragma unroll
        for (int nt = 0; nt < 8; ++nt) {
            bf16x8 vf = *(const bf16x8*)(B32 + ((tt - 4) * 128 + nt * 16 + lm) * 32 + q * 8);
            o[nt] = __builtin_amdgcn_mfma_f32_16x16x32_bf16(pf, vf, o[nt], 0, 0, 0);
        }
    }
    __syncthreads();   // V reads + P reads done

    // ---- issue Wm stage; write O -> Ot (Ps overlay, A-layout) ----
#pragma unroll
    for (int ss = 0; ss < 4; ++ss)
#pragma unroll
        for (int i = 0; i < 2; ++i) {
            int n = w * 32 + i * 16 + l4r;
            cp16(wmt + (size_t)n * 128 + ss * 32 + l4c,
                 (void*)(B32 + (ss * 128 + w * 32 + i * 16) * 32));
        }
    u16* Ot = Ps;   // [64][136]
#pragma unroll
    for (int r = 0; r < 4; ++r) {
        int rl = w * 16 + q * 4 + r;
#pragma unroll
        for (int nt = 0; nt < 8; ++nt)
            Ot[rl * 136 + nt * 16 + lm] = f2b(o[nt][r]);
    }
    __syncthreads();

    // ---- msg = O @ WmT^T (all-LDS) ----
    f32x4 macc[8];
#pragma unroll
    for (int n2 = 0; n2 < 8; ++n2) { f32x4 z = {0.f, 0.f, 0.f, 0.f}; macc[n2] = z; }
#pragma unroll
    for (int kt = 0; kt < 4; ++kt) {
        bf16x8 paf = *(const bf16x8*)(Ot + (w * 16 + lm) * 136 + kt * 32 + q * 8);
#pragma unroll
        for (int n2 = 0; n2 < 8; ++n2) {
            bf16x8 wf = *(const bf16x8*)(B32 + (kt * 128 + n2 * 16 + lm) * 32 + q * 8);
            macc[n2] = __builtin_amdgcn_mfma_f32_16x16x32_bf16(paf, wf, macc[n2], 0, 0, 0);
        }
    }

    // ---- row LN + store (source-order rows) ----
    float gv[8], bv[8];
#pragma unroll
    for (int n2 = 0; n2 < 8; ++n2) {
        int col = n2 * 16 + lm;
        gv[n2] = g[col]; bv[n2] = bb[col];
    }
#pragma unroll
    for (int r = 0; r < 4; ++r) {
        float s1 = 0.f, s2 = 0.f;
#pragma unroll
        for (int n2 = 0; n2 < 8; ++n2) {
            float v = macc[n2][r];
            s1 += v; s2 += v * v;
        }
        s1 += __shfl_xor(s1, 1); s2 += __shfl_xor(s2, 1);
        s1 += __shfl_xor(s1, 2); s2 += __shfl_xor(s2, 2);
        s1 += __shfl_xor(s1, 4); s2 += __shfl_xor(s2, 4);
        s1 += __shfl_xor(s1, 8); s2 += __shfl_xor(s2, 8);
        float mean = s1 * (1.f / 128.f);
        float var = fmaxf(s2 * (1.f / 128.f) - mean * mean, 0.f);
        float rs = rsqrtf(var + 1e-5f);
        int t = q0 + w * 16 + q * 4 + r;
        int ii = t >> 4, jj = t & 15;
        int h = (wi * 16 + ii + 8) & 127;
        int w2 = (wj * 16 + jj + 8) & 127;
        size_t orow = ((size_t)b * 16384 + h * 128 + w2) * 128;
#pragma unroll
        for (int n2 = 0; n2 < 8; ++n2)
            msgb[orow + n2 * 16 + lm] = f2b((macc[n2][r] - mean) * rs * gv[n2] + bv[n2]);
    }
}

// ---------------------------------------------------------------------------
// FUSED FFN (R11, frozen): out = resid + LN(gelu(cat(src,msg)@W1)@W2).
// Grid 512 (64 rows/block), 512 thr (8 waves), 72KB LDS -> 2 blocks/CU.
// ---------------------------------------------------------------------------
__global__ __launch_bounds__(512, 4)
void fused_ffn(const u16* __restrict__ A0, const u16* __restrict__ A1,
               const u16* __restrict__ W1T, const u16* __restrict__ W2T,
               const float* __restrict__ g, const float* __restrict__ bb,
               const float* __restrict__ resid, float* __restrict__ outv)
{
    __shared__ __align__(16) u16 W1s[16384];    // [8 ks][64 hid][32] 32KB single
    __shared__ __align__(16) u16 W2s[16384];    // [2 buf][2 ks][128 col][32] 32KB
    __shared__ __align__(16) u16 Gs[4096];      // [64 tok][64 k] swizzled 8KB

    const int tid = threadIdx.x;
    const int w = tid >> 6, lane = tid & 63;    // w in 0..7
    const int lm = lane & 15, q = lane >> 4;
    const int l4r = lane >> 2, l4c = (lane & 3) * 8;
    const int wm = w >> 2, wn = w & 3;          // wm: tok-32 half, wn: hid16/col32
    const int m0 = blockIdx.x * 64;

    const u16* w1p = W1T + (size_t)l4r * 256 + w * 32 + l4c;
    const u16* w2p = W2T + (size_t)((w & 3) * 32 + l4r) * 1024 + (w >> 2) * 32 + l4c;
    u16* const w1d = W1s + (w * 64) * 32;
    u16* const w2d0 = W2s + (((w >> 2) * 128 + (w & 3) * 32)) * 32;
    u16* const w2d1 = w2d0 + 8192;

    // ---- A -> regs (one-time): tokens wm*32+mt*16+lm over K=256 ----
    bf16x8 areg[2][8];
#pragma unroll
    for (int mt = 0; mt < 2; ++mt)
#pragma unroll
        for (int ks = 0; ks < 8; ++ks) {
            const u16* Ab = (ks < 4) ? A0 : A1;
            areg[mt][ks] = *(const bf16x8*)(
                Ab + (size_t)(m0 + wm * 32 + mt * 16 + lm) * 128 + (ks & 3) * 32 + q * 8);
        }

    // ---- prologue: stage W1(0) -> W1s, W2(0) -> buf0 ----
#pragma unroll
    for (int i = 0; i < 4; ++i)
        cp16(w1p + (size_t)(i * 16) * 256, w1d + (i * 16) * 32);
#pragma unroll
    for (int i = 0; i < 2; ++i)
        cp16(w2p + (size_t)(i * 16) * 1024, w2d0 + (i * 16) * 32);
    w1p += 16384; w2p += 64;
    __syncthreads();                              // W(0) landed

    f32x4 acc2[2][2] = {};                        // 32x32 out tile per wave
#pragma unroll 2
    for (int c = 0; c < 16; ++c) {
        const int cb = c & 1, nb = cb ^ 1;

        // ---- ffn1(c): W1s + areg -> gelu -> Gs ----
        {
            f32x4 acc1[2] = {};
#pragma unroll
            for (int ks = 0; ks < 8; ++ks) {
                bf16x8 w1f = *(const bf16x8*)(W1s + (ks * 64 + wn * 16 + lm) * 32 + q * 8);
#pragma unroll
                for (int mt = 0; mt < 2; ++mt)
                    acc1[mt] = __builtin_amdgcn_mfma_f32_16x16x32_bf16(
                        w1f, areg[mt][ks], acc1[mt], 0, 0, 0);
            }
#pragma unroll
            for (int mt = 0; mt < 2; ++mt) {
                float g0 = gelu_e(acc1[mt][0]), g1 = gelu_e(acc1[mt][1]);
                float g2 = gelu_e(acc1[mt][2]), g3 = gelu_e(acc1[mt][3]);
                unsigned p0, p1;
                asm("v_cvt_pk_bf16_f32 %0, %1, %2" : "=v"(p0) : "v"(g0), "v"(g1));
                asm("v_cvt_pk_bf16_f32 %0, %1, %2" : "=v"(p1) : "v"(g2), "v"(g3));
                int tok = wm * 32 + mt * 16 + lm;
                int slot = (wn * 2 + (q >> 1)) ^ (tok & 7);
                u32x2 pk; pk[0] = p0; pk[1] = p1;
                *(u32x2*)(Gs + tok * 64 + slot * 8 + (q & 1) * 4) = pk;
            }
        }
        __syncthreads();   // Gs visible; all W1s(c) reads done -> W1s free

        // ---- stage W1(c+1) -> W1s, W2(c+1) -> buf[nb] (lands by next bar) ----
        if (c + 1 < 16) {
#pragma unroll
            for (int i = 0; i < 4; ++i)
                cp16(w1p + (size_t)(i * 16) * 256, w1d + (i * 16) * 32);
            u16* d = nb ? w2d1 : w2d0;
#pragma unroll
            for (int i = 0; i < 2; ++i)
                cp16(w2p + (size_t)(i * 16) * 1024, d + (i * 16) * 32);
        }
        w1p += 16384; w2p += 64;

        // ---- ffn2(c): Gs + W2s[cb] -> acc2 ----
        {
            const u16* W2c = W2s + cb * 8192;
#pragma unroll
            for (int ks = 0; ks < 2; ++ks) {
                bf16x8 pa[2], wf[2];
#pragma unroll
                for (int mt = 0; mt < 2; ++mt) {
                    int tok = wm * 32 + mt * 16 + lm;
                    pa[mt] = *(const bf16x8*)(Gs + tok * 64 + (((ks * 4 + q) ^ (tok & 7)) * 8));
                }
#pragma unroll
                for (int nt = 0; nt < 2; ++nt)
                    wf[nt] = *(const bf16x8*)(W2c + (ks * 128 + wn * 32 + nt * 16 + lm) * 32 + q * 8);
#pragma unroll
                for (int mt = 0; mt < 2; ++mt)
#pragma unroll
                    for (int nt = 0; nt < 2; ++nt)
                        acc2[mt][nt] = __builtin_amdgcn_mfma_f32_16x16x32_bf16(
                            pa[mt], wf[nt], acc2[mt][nt], 0, 0, 0);
            }
        }
        __syncthreads();   // drains vmcnt (W(c+1) landed); Gs reads done
    }

    // ---- LN + residual epilogue (stats exchange overlaid on Gs) ----
    float* stats = (float*)Gs;                   // [64][8] = 2KB
#pragma unroll
    for (int mt = 0; mt < 2; ++mt)
#pragma unroll
        for (int r = 0; r < 4; ++r) {
            float s1 = 0.f, s2 = 0.f;
#pragma unroll
            for (int nt = 0; nt < 2; ++nt) {
                float v = acc2[mt][nt][r];
                s1 += v; s2 += v * v;
            }
            s1 += __shfl_xor(s1, 1); s2 += __shfl_xor(s2, 1);
            s1 += __shfl_xor(s1, 2); s2 += __shfl_xor(s2, 2);
            s1 += __shfl_xor(s1, 4); s2 += __shfl_xor(s2, 4);
            s1 += __shfl_xor(s1, 8); s2 += __shfl_xor(s2, 8);
            if (lm == 0) {
                int row = wm * 32 + mt * 16 + q * 4 + r;
                stats[row * 8 + wn * 2] = s1;
                stats[row * 8 + wn * 2 + 1] = s2;
            }
        }
    __syncthreads();

    float gv[2], bv[2];
#pragma unroll
    for (int nt = 0; nt < 2; ++nt) {
        int col = wn * 32 + nt * 16 + lm;
        gv[nt] = g[col]; bv[nt] = bb[col];
    }
#pragma unroll
    for (int mt = 0; mt < 2; ++mt)
#pragma unroll
        for (int r = 0; r < 4; ++r) {
            int row = wm * 32 + mt * 16 + q * 4 + r;
            f32x4 st0 = *(const f32x4*)(stats + row * 8);
            f32x4 st1 = *(const f32x4*)(stats + row * 8 + 4);
            float s1 = st0[0] + st0[2] + st1[0] + st1[2];
            float s2 = st0[1] + st0[3] + st1[1] + st1[3];
            float mean = s1 * (1.f / 128.f);
            float var = fmaxf(s2 * (1.f / 128.f) - mean * mean, 0.f);
            float rs = rsqrtf(var + 1e-5f);
#pragma unroll
            for (int nt = 0; nt < 2; ++nt) {
                int col = wn * 32 + nt * 16 + lm;
                size_t gi = (size_t)(m0 + row) * 128 + col;
                outv[gi] = (acc2[mt][nt][r] - mean) * rs * gv[nt] + bv[nt] + resid[gi];
            }
        }
}

// ---------------------------------------------------------------------------
// Prep (merged): weight transposes write-coalesced; fp32->bf16 act cast.
// ---------------------------------------------------------------------------
__global__ void prep_all(const float* __restrict__ Wq, const float* __restrict__ Wk,
                         const float* __restrict__ Wv, const float* __restrict__ Wm,
                         const float* __restrict__ W1, const float* __restrict__ W2,
                         const float* __restrict__ src, const float* __restrict__ tgt,
                         u16* __restrict__ ws, u16* __restrict__ srcb,
                         u16* __restrict__ tgtb)
{
    int bx = blockIdx.x;
    if (bx < 1792) {
        int idx = bx * 256 + threadIdx.x;
        if (idx < 65536) {                       // Wq,Wk,Wv,Wm: 128x128
            int m = idx >> 14, e = idx & 16383;
            const float* sp = (m == 0) ? Wq : (m == 1) ? Wk : (m == 2) ? Wv : Wm;
            int n = e >> 7, k = e & 127;
            ws[m * 16384 + n * 128 + k] = f2b(sp[k * 128 + n]);
        } else if (idx < 327680) {               // W1 (256,1024) -> (1024,256)
            int e = idx - 65536;
            int n = e >> 8, k = e & 255;
            ws[65536 + n * 256 + k] = f2b(W1[k * 1024 + n]);
        } else {                                  // W2 (1024,128) -> (128,1024)
            int e = idx - 327680;
            int n = e >> 10, k = e & 1023;
            ws[327680 + n * 1024 + k] = f2b(W2[k * 128 + n]);
        }
    } else {
        int idx = (bx - 1792) * 256 + threadIdx.x;   // 0..2097151
        const float* s; u16* d; int i;
        if (idx < 1048576) { s = src; d = srcb; i = idx * 4; }
        else               { s = tgt; d = tgtb; i = (idx - 1048576) * 4; }
        f32x4 v = *(const f32x4*)(s + i);
        u16x4 o; o[0] = f2b(v[0]); o[1] = f2b(v[1]); o[2] = f2b(v[2]); o[3] = f2b(v[3]);
        *(u16x4*)(d + i) = o;
    }
}

// ---------------------------------------------------------------------------
// Workspace layout (u16 element offsets)
// ---------------------------------------------------------------------------
#define OFF_WQT  0u            // concat [WqT;WkT;WvT] 3x(128x128)
#define OFF_WMT  49152u
#define OFF_W1T  65536u
#define OFF_W2T  327680u
#define OFF_SRCB 458752u
#define OFF_TGTB 4653056u
#define OFF_QW   8847360u
#define OFF_KW   13041664u
#define OFF_VWT  17235968u
#define OFF_MSGB 21430272u     // bf16 msg, source-order; ends 25624576

extern "C" void kernel_launch(void* const* d_in, const int* in_sizes, int n_in,
                              void* d_out, int out_size, void* d_ws, size_t ws_size,
                              hipStream_t stream)
{
    (void)in_sizes; (void)n_in; (void)out_size; (void)ws_size;
    const float* source = (const float*)d_in[0];
    const float* target = (const float*)d_in[1];
    const float* Wq = (const float*)d_in[2];
    const float* Wk = (const float*)d_in[3];
    const float* Wv = (const float*)d_in[4];
    const float* Wm = (const float*)d_in[5];
    const float* g1 = (const float*)d_in[6];
    const float* b1 = (const float*)d_in[7];
    const float* W1 = (const float*)d_in[8];
    const float* W2 = (const float*)d_in[9];
    const float* g2 = (const float*)d_in[10];
    const float* b2 = (const float*)d_in[11];
    u16* ws = (u16*)d_ws;
    float* out = (float*)d_out;

    prep_all<<<9984, 256, 0, stream>>>(Wq, Wk, Wv, Wm, W1, W2, source, target,
                                       ws, ws + OFF_SRCB, ws + OFF_TGTB);
    gemm_qkv<<<dim3(256, 3), 256, 0, stream>>>(
        ws + OFF_SRCB, ws + OFF_TGTB, ws + OFF_WQT,
        ws + OFF_QW, ws + OFF_KW, ws + OFF_VWT);
    attn_msg<<<512, 256, 0, stream>>>(
        ws + OFF_QW, ws + OFF_KW, ws + OFF_VWT, ws + OFF_WMT, g1, b1,
        ws + OFF_MSGB);
    fused_ffn<<<512, 512, 0, stream>>>(
        ws + OFF_SRCB, ws + OFF_MSGB, ws + OFF_W1T, ws + OFF_W2T,
        g2, b2, source, out);
}

// Round 6
// 186.368 us; speedup vs baseline: 1.0526x; 1.0125x over previous
//
#include <hip/hip_runtime.h>
#include <math.h>
#include <stdint.h>

// ---------------------------------------------------------------------------
// TransformerLayer (Swin-style) on MI355X. FP32 I/O; bf16 MFMA internals.
// B=2, H=W=128, C=128, NS=8 -> 64 windows x 256 tokens; HID=1024.
// R13: prep_all weight transposes rebuilt as LDS-tiled (coalesced both
//      directions; kills ~28MB sector overfetch). T5 s_setprio(1) wrapped
//      around MFMA clusters in fused_ffn (2-block/CU role diversity) and
//      attn_msg. fused_ffn/attn/qkv structure otherwise frozen (R11/R12).
// ---------------------------------------------------------------------------

typedef unsigned short u16;
typedef __attribute__((ext_vector_type(8))) short bf16x8;   // 8 bf16 (4 VGPRs)
typedef __attribute__((ext_vector_type(4))) float f32x4;
typedef __attribute__((ext_vector_type(4))) short u16x4;
typedef __attribute__((ext_vector_type(2))) unsigned int u32x2;

__device__ __forceinline__ u16 f2b(float f) {
    unsigned int i = __float_as_uint(f);
    unsigned int r = (i + 0x7fffu + ((i >> 16) & 1u)) >> 16;
    return (u16)r;
}

// gelu via A-S 7.1.28 erf (|eps|<=5e-4): ONE transcendental (rcp).
__device__ __forceinline__ float gelu_e(float x) {
    float y = fabsf(x) * 0.70710678118f;
    float u = fmaf(y, fmaf(y, fmaf(y, fmaf(y, 0.078108f, 0.000972f),
                                   0.230389f), 0.278393f), 1.0f);
    u = u * u; u = u * u;
    float r = __builtin_amdgcn_rcpf(u);
    return fmaxf(x, 0.f) - 0.5f * fabsf(x) * r;
}

// 16B async global->LDS (m97-verified). LDS dest wave-uniform base + lane*16.
__device__ __forceinline__ void cp16(const void* g, void* l) {
    auto* gp = reinterpret_cast<const __attribute__((address_space(1))) unsigned int*>(
        reinterpret_cast<uintptr_t>(g));
    auto* lp = reinterpret_cast<__attribute__((address_space(3))) unsigned int*>(
        reinterpret_cast<uintptr_t>(l));
    __builtin_amdgcn_global_load_lds(gp, lp, 16, 0, 0);
}

// window row (b*16384 + win*256 + t) -> source-order row (b*16384 + h*128 + w)
__device__ __forceinline__ int win_map(int gm) {
    int b = gm >> 14, rr = gm & 16383;
    int win = rr >> 8, t = rr & 255;
    int wi = win >> 3, wj = win & 7, i = t >> 4, j = t & 15;
    int h = (wi * 16 + i + 8) & 127;
    int w = (wj * 16 + j + 8) & 127;
    return (b << 14) + h * 128 + w;
}

// ---------------------------------------------------------------------------
// Fused QKV (R12): grid (256, 3). A frags global->reg; LDS = B + epilogue
// overlay only (34.8KB) -> 3 blocks/CU.
// ---------------------------------------------------------------------------
__global__ __launch_bounds__(256, 3)
void gemm_qkv(const u16* __restrict__ srcb, const u16* __restrict__ tgtb,
              const u16* __restrict__ Bt, u16* __restrict__ qw,
              u16* __restrict__ kw, u16* __restrict__ vwt)
{
    __shared__ __align__(16) u16 SMEM[17408];   // Bs[4][128][32] | Ts 128x136
    u16* Bs = SMEM;
    u16* Ts = SMEM;

    const int tid = threadIdx.x;
    const int w = tid >> 6, lane = tid & 63;
    const int lm = lane & 15, q = lane >> 4;
    const int wm = w >> 1, wn = w & 1;
    const int m0 = blockIdx.x * 128;
    const int y = blockIdx.y;
    const u16* Ab = (y == 0) ? srcb : tgtb;

    // ---- stage B (32KB) -> LDS ----
#pragma unroll
    for (int s = 0; s < 4; ++s)
#pragma unroll
        for (int i = 0; i < 2; ++i) {
            int row = w * 32 + i * 16 + (lane >> 2);
            int kc = s * 32 + (lane & 3) * 8;
            cp16(Bt + (size_t)(y * 128 + row) * 128 + kc,
                 (void*)(Bs + (s * 128 + w * 32 + i * 16) * 32));
        }

    // ---- A fragments: global -> registers (issued before barrier) ----
    bf16x8 af[4][4];
#pragma unroll
    for (int t = 0; t < 4; ++t) {
        int row = win_map(m0 + wm * 64 + t * 16 + lm);
#pragma unroll
        for (int s = 0; s < 4; ++s)
            af[t][s] = *(const bf16x8*)(Ab + (size_t)row * 128 + s * 32 + q * 8);
    }
    __syncthreads();   // B landed (also drains af loads)

    f32x4 acc[4][4] = {};
    __builtin_amdgcn_s_setprio(1);
#pragma unroll
    for (int s = 0; s < 4; ++s) {
        bf16x8 bfr[4];
#pragma unroll
        for (int t = 0; t < 4; ++t)
            bfr[t] = *(const bf16x8*)(Bs + (s * 128 + wn * 64 + t * 16 + lm) * 32 + q * 8);
#pragma unroll
        for (int mt = 0; mt < 4; ++mt)
#pragma unroll
            for (int nt = 0; nt < 4; ++nt)
                acc[mt][nt] = __builtin_amdgcn_mfma_f32_16x16x32_bf16(
                    af[mt][s], bfr[nt], acc[mt][nt], 0, 0, 0);
    }
    __builtin_amdgcn_s_setprio(0);

    __syncthreads();
#pragma unroll
    for (int mt = 0; mt < 4; ++mt)
#pragma unroll
        for (int nt = 0; nt < 4; ++nt)
#pragma unroll
            for (int r = 0; r < 4; ++r) {
                int rowl = wm * 64 + mt * 16 + q * 4 + r;
                int col = wn * 64 + nt * 16 + lm;
                int idx = (y == 2) ? col * 136 + rowl : rowl * 136 + col;
                Ts[idx] = f2b(acc[mt][nt][r]);
            }
    __syncthreads();
    const int c8 = (tid & 15) * 8;
#pragma unroll
    for (int i = 0; i < 8; ++i) {
        int rr = i * 16 + (tid >> 4);
        bf16x8 t = *(const bf16x8*)(Ts + rr * 136 + c8);
        if (y == 2) {
            int wix = m0 >> 8, tok0 = m0 & 255;   // vwT[(b*64+win)*128+ch][tok]
            *(bf16x8*)(vwt + (size_t)wix * 32768 + (size_t)rr * 256 + tok0 + c8) = t;
        } else {
            u16* Cv = (y == 0) ? qw : kw;
            *(bf16x8*)(Cv + (size_t)(m0 + rr) * 128 + c8) = t;
        }
    }
}

// ---------------------------------------------------------------------------
// Fused attention + msg-proj + LayerNorm (R12 XCD remap + R13 setprio).
// One block = 64 Q rows of a window; grid 512. LDS: Ps 33.8KB + B32 32KB.
// ---------------------------------------------------------------------------
__global__ __launch_bounds__(256, 2)
void attn_msg(const u16* __restrict__ qw, const u16* __restrict__ kw,
              const u16* __restrict__ vt, const u16* __restrict__ wmt,
              const float* __restrict__ g, const float* __restrict__ bb,
              u16* __restrict__ msgb)
{
    __shared__ __align__(16) u16 Ps[64 * 264];   // P (stride 264); Q/Ot overlays
    __shared__ __align__(16) u16 B32[16384];     // 32KB staging buffer

    const int tid = threadIdx.x, w = tid >> 6, lane = tid & 63;
    const int lm = lane & 15, q = lane >> 4;
    const int l4r = lane >> 2, l4c = (lane & 3) * 8;
    const int bid = blockIdx.x;
    const int qc = bid >> 7;                     // XCD-affinity remap (R12)
    const int gwin = bid & 127;
    const int win = gwin & 63, b = gwin >> 6;
    const int wi = win >> 3, wj = win & 7;
    const int q0 = qc * 64;
    const size_t wbase = (size_t)(b * 64 + win);
    const u16* kwb = kw + wbase * 256 * 128;
    const u16* qwb = qw + wbase * 256 * 128;
    const u16* vtb = vt + wbase * 128 * 256;

    // ---- stage Q (Ps overlay, [4 kt][64 row][32]) + K tok[0,128) ----
    u16* Qs = Ps;
#pragma unroll
    for (int i = 0; i < 4; ++i)
        cp16(qwb + (size_t)(q0 + w * 16 + l4r) * 128 + i * 32 + l4c,
             (void*)(Qs + (i * 64 + w * 16) * 32));
#pragma unroll
    for (int s = 0; s < 4; ++s)
#pragma unroll
        for (int i = 0; i < 2; ++i) {
            int tok = w * 32 + i * 16 + l4r;
            cp16(kwb + (size_t)tok * 128 + s * 32 + l4c,
                 (void*)(B32 + (s * 128 + w * 32 + i * 16) * 32));
        }
    __syncthreads();

    bf16x8 af[4];
#pragma unroll
    for (int kt = 0; kt < 4; ++kt)
        af[kt] = *(const bf16x8*)(Qs + (kt * 64 + w * 16 + lm) * 32 + q * 8);

    f32x4 s[16];
#pragma unroll
    for (int nt = 0; nt < 16; ++nt) { f32x4 z = {0.f, 0.f, 0.f, 0.f}; s[nt] = z; }
    __builtin_amdgcn_s_setprio(1);
#pragma unroll
    for (int kt = 0; kt < 4; ++kt)
#pragma unroll
        for (int nt = 0; nt < 8; ++nt) {
            bf16x8 bf = *(const bf16x8*)(B32 + (kt * 128 + nt * 16 + lm) * 32 + q * 8);
            s[nt] = __builtin_amdgcn_mfma_f32_16x16x32_bf16(af[kt], bf, s[nt], 0, 0, 0);
        }
    __builtin_amdgcn_s_setprio(0);
    __syncthreads();
    // ---- K tok[128,256) ----
#pragma unroll
    for (int ss = 0; ss < 4; ++ss)
#pragma unroll
        for (int i = 0; i < 2; ++i) {
            int tok = 128 + w * 32 + i * 16 + l4r;
            cp16(kwb + (size_t)tok * 128 + ss * 32 + l4c,
                 (void*)(B32 + (ss * 128 + w * 32 + i * 16) * 32));
        }
    __syncthreads();
    __builtin_amdgcn_s_setprio(1);
#pragma unroll
    for (int kt = 0; kt < 4; ++kt)
#pragma unroll
        for (int nt = 8; nt < 16; ++nt) {
            bf16x8 bf = *(const bf16x8*)(B32 + (kt * 128 + (nt - 8) * 16 + lm) * 32 + q * 8);
            s[nt] = __builtin_amdgcn_mfma_f32_16x16x32_bf16(af[kt], bf, s[nt], 0, 0, 0);
        }
    __builtin_amdgcn_s_setprio(0);
    __syncthreads();   // B32 reads done -> free for V

    // ---- issue V tok[0,128) load, then softmax (overlap) ----
#pragma unroll
    for (int tt = 0; tt < 4; ++tt)
#pragma unroll
        for (int i = 0; i < 2; ++i) {
            int ch = w * 32 + i * 16 + l4r;
            cp16(vtb + (size_t)ch * 256 + tt * 32 + l4c,
                 (void*)(B32 + (tt * 128 + w * 32 + i * 16) * 32));
        }

    // analytic Swin mask + softmax (regs), P -> Ps
    int idk[16];
#pragma unroll
    for (int nt = 0; nt < 16; ++nt) {
        int rh = (wi == 7) ? ((nt >= 8) ? 2 : 1) : 0;
        int rw = (wj == 7) ? ((lm >= 8) ? 2 : 1) : 0;
        idk[nt] = rh * 3 + rw;
    }
    const float scale = 0.08838834764831845f;
#pragma unroll
    for (int r = 0; r < 4; ++r) {
        int tq = q0 + w * 16 + q * 4 + r;
        int iq = tq >> 4, jq = tq & 15;
        int rhq = (wi == 7) ? ((iq >= 8) ? 2 : 1) : 0;
        int rwq = (wj == 7) ? ((jq >= 8) ? 2 : 1) : 0;
        int idq = rhq * 3 + rwq;
        float sv[16];
        float mx = -1e30f;
#pragma unroll
        for (int nt = 0; nt < 16; ++nt) {
            float x = s[nt][r] * scale + ((idq != idk[nt]) ? -100.f : 0.f);
            sv[nt] = x; mx = fmaxf(mx, x);
        }
        mx = fmaxf(mx, __shfl_xor(mx, 1));
        mx = fmaxf(mx, __shfl_xor(mx, 2));
        mx = fmaxf(mx, __shfl_xor(mx, 4));
        mx = fmaxf(mx, __shfl_xor(mx, 8));
        float sum = 0.f;
#pragma unroll
        for (int nt = 0; nt < 16; ++nt) { float e = __expf(sv[nt] - mx); sv[nt] = e; sum += e; }
        sum += __shfl_xor(sum, 1);
        sum += __shfl_xor(sum, 2);
        sum += __shfl_xor(sum, 4);
        sum += __shfl_xor(sum, 8);
        float inv = 1.0f / sum;
#pragma unroll
        for (int nt = 0; nt < 16; ++nt)
            Ps[(w * 16 + q * 4 + r) * 264 + nt * 16 + lm] = f2b(sv[nt] * inv);
    }
    __syncthreads();   // V0 loaded (barrier drains vmcnt) + P visible

    // ---- PV tok[0,128) ----
    f32x4 o[8];
#pragma unroll
    for (int nt = 0; nt < 8; ++nt) { f32x4 z = {0.f, 0.f, 0.f, 0.f}; o[nt] = z; }
    __builtin_amdgcn_s_setprio(1);
#pragma unroll
    for (int tt = 0; tt < 4; ++tt) {
        bf16x8 pf = *(const bf16x8*)(Ps + (w * 16 + lm) * 264 + tt * 32 + q * 8);
#pragma unroll
        for (int nt = 0; nt < 8; ++nt) {
            bf16x8 vf = *(const bf16x8*)(B32 + (tt * 128 + nt * 16 + lm) * 32 + q * 8);
            o[nt] = __builtin_amdgcn_mfma_f32_16x16x32_bf16(pf, vf, o[nt], 0, 0, 0);
        }
    }
    __builtin_amdgcn_s_setprio(0);
    __syncthreads();
    // ---- V tok[128,256) ----
#pragma unroll
    for (int tt = 0; tt < 4; ++tt)
#pragma unroll
        for (int i = 0; i < 2; ++i) {
            int ch = w * 32 + i * 16 + l4r;
            cp16(vtb + (size_t)ch * 256 + 128 + tt * 32 + l4c,
                 (void*)(B32 + (tt * 128 + w * 32 + i * 16) * 32));
        }
    __syncthreads();
    __builtin_amdgcn_s_setprio(1);
#pragma unroll
    for (int tt = 4; tt < 8; ++tt) {
        bf16x8 pf = *(const bf16x8*)(Ps + (w * 16 + lm) * 264 + tt * 32 + q * 8);
#pragma unroll
        for (int nt = 0; nt < 8; ++nt) {
            bf16x8 vf = *(const bf16x8*)(B32 + ((tt - 4) * 128 + nt * 16 + lm) * 32 + q * 8);
            o[nt] = __builtin_amdgcn_mfma_f32_16x16x32_bf16(pf, vf, o[nt], 0, 0, 0);
        }
    }
    __builtin_amdgcn_s_setprio(0);
    __syncthreads();   // V reads + P reads done

    // ---- issue Wm stage; write O -> Ot (Ps overlay, A-layout) ----
#pragma unroll
    for (int ss = 0; ss < 4; ++ss)
#pragma unroll
        for (int i = 0; i < 2; ++i) {
            int n = w * 32 + i * 16 + l4r;
            cp16(wmt + (size_t)n * 128 + ss * 32 + l4c,
                 (void*)(B32 + (ss * 128 + w * 32 + i * 16) * 32));
        }
    u16* Ot = Ps;   // [64][136]
#pragma unroll
    for (int r = 0; r < 4; ++r) {
        int rl = w * 16 + q * 4 + r;
#pragma unroll
        for (int nt = 0; nt < 8; ++nt)
            Ot[rl * 136 + nt * 16 + lm] = f2b(o[nt][r]);
    }
    __syncthreads();

    // ---- msg = O @ WmT^T (all-LDS) ----
    f32x4 macc[8];
#pragma unroll
    for (int n2 = 0; n2 < 8; ++n2) { f32x4 z = {0.f, 0.f, 0.f, 0.f}; macc[n2] = z; }
    __builtin_amdgcn_s_setprio(1);
#pragma unroll
    for (int kt = 0; kt < 4; ++kt) {
        bf16x8 paf = *(const bf16x8*)(Ot + (w * 16 + lm) * 136 + kt * 32 + q * 8);
#pragma unroll
        for (int n2 = 0; n2 < 8; ++n2) {
            bf16x8 wf = *(const bf16x8*)(B32 + (kt * 128 + n2 * 16 + lm) * 32 + q * 8);
            macc[n2] = __builtin_amdgcn_mfma_f32_16x16x32_bf16(paf, wf, macc[n2], 0, 0, 0);
        }
    }
    __builtin_amdgcn_s_setprio(0);

    // ---- row LN + store (source-order rows) ----
    float gv[8], bv[8];
#pragma unroll
    for (int n2 = 0; n2 < 8; ++n2) {
        int col = n2 * 16 + lm;
        gv[n2] = g[col]; bv[n2] = bb[col];
    }
#pragma unroll
    for (int r = 0; r < 4; ++r) {
        float s1 = 0.f, s2 = 0.f;
#pragma unroll
        for (int n2 = 0; n2 < 8; ++n2) {
            float v = macc[n2][r];
            s1 += v; s2 += v * v;
        }
        s1 += __shfl_xor(s1, 1); s2 += __shfl_xor(s2, 1);
        s1 += __shfl_xor(s1, 2); s2 += __shfl_xor(s2, 2);
        s1 += __shfl_xor(s1, 4); s2 += __shfl_xor(s2, 4);
        s1 += __shfl_xor(s1, 8); s2 += __shfl_xor(s2, 8);
        float mean = s1 * (1.f / 128.f);
        float var = fmaxf(s2 * (1.f / 128.f) - mean * mean, 0.f);
        float rs = rsqrtf(var + 1e-5f);
        int t = q0 + w * 16 + q * 4 + r;
        int ii = t >> 4, jj = t & 15;
        int h = (wi * 16 + ii + 8) & 127;
        int w2 = (wj * 16 + jj + 8) & 127;
        size_t orow = ((size_t)b * 16384 + h * 128 + w2) * 128;
#pragma unroll
        for (int n2 = 0; n2 < 8; ++n2)
            msgb[orow + n2 * 16 + lm] = f2b((macc[n2][r] - mean) * rs * gv[n2] + bv[n2]);
    }
}

// ---------------------------------------------------------------------------
// FUSED FFN (R11 structure + R13 setprio): out = resid + LN(gelu(A@W1)@W2).
// Grid 512 (64 rows/block), 512 thr (8 waves), 72KB LDS -> 2 blocks/CU.
// ---------------------------------------------------------------------------
__global__ __launch_bounds__(512, 4)
void fused_ffn(const u16* __restrict__ A0, const u16* __restrict__ A1,
               const u16* __restrict__ W1T, const u16* __restrict__ W2T,
               const float* __restrict__ g, const float* __restrict__ bb,
               const float* __restrict__ resid, float* __restrict__ outv)
{
    __shared__ __align__(16) u16 W1s[16384];    // [8 ks][64 hid][32] 32KB single
    __shared__ __align__(16) u16 W2s[16384];    // [2 buf][2 ks][128 col][32] 32KB
    __shared__ __align__(16) u16 Gs[4096];      // [64 tok][64 k] swizzled 8KB

    const int tid = threadIdx.x;
    const int w = tid >> 6, lane = tid & 63;    // w in 0..7
    const int lm = lane & 15, q = lane >> 4;
    const int l4r = lane >> 2, l4c = (lane & 3) * 8;
    const int wm = w >> 2, wn = w & 3;          // wm: tok-32 half, wn: hid16/col32
    const int m0 = blockIdx.x * 64;

    const u16* w1p = W1T + (size_t)l4r * 256 + w * 32 + l4c;
    const u16* w2p = W2T + (size_t)((w & 3) * 32 + l4r) * 1024 + (w >> 2) * 32 + l4c;
    u16* const w1d = W1s + (w * 64) * 32;
    u16* const w2d0 = W2s + (((w >> 2) * 128 + (w & 3) * 32)) * 32;
    u16* const w2d1 = w2d0 + 8192;

    // ---- A -> regs (one-time): tokens wm*32+mt*16+lm over K=256 ----
    bf16x8 areg[2][8];
#pragma unroll
    for (int mt = 0; mt < 2; ++mt)
#pragma unroll
        for (int ks = 0; ks < 8; ++ks) {
            const u16* Ab = (ks < 4) ? A0 : A1;
            areg[mt][ks] = *(const bf16x8*)(
                Ab + (size_t)(m0 + wm * 32 + mt * 16 + lm) * 128 + (ks & 3) * 32 + q * 8);
        }

    // ---- prologue: stage W1(0) -> W1s, W2(0) -> buf0 ----
#pragma unroll
    for (int i = 0; i < 4; ++i)
        cp16(w1p + (size_t)(i * 16) * 256, w1d + (i * 16) * 32);
#pragma unroll
    for (int i = 0; i < 2; ++i)
        cp16(w2p + (size_t)(i * 16) * 1024, w2d0 + (i * 16) * 32);
    w1p += 16384; w2p += 64;
    __syncthreads();                              // W(0) landed

    f32x4 acc2[2][2] = {};                        // 32x32 out tile per wave
#pragma unroll 2
    for (int c = 0; c < 16; ++c) {
        const int cb = c & 1, nb = cb ^ 1;

        // ---- ffn1(c): W1s + areg -> gelu -> Gs ----
        {
            f32x4 acc1[2] = {};
            __builtin_amdgcn_s_setprio(1);
#pragma unroll
            for (int ks = 0; ks < 8; ++ks) {
                bf16x8 w1f = *(const bf16x8*)(W1s + (ks * 64 + wn * 16 + lm) * 32 + q * 8);
#pragma unroll
                for (int mt = 0; mt < 2; ++mt)
                    acc1[mt] = __builtin_amdgcn_mfma_f32_16x16x32_bf16(
                        w1f, areg[mt][ks], acc1[mt], 0, 0, 0);
            }
            __builtin_amdgcn_s_setprio(0);
#pragma unroll
            for (int mt = 0; mt < 2; ++mt) {
                float g0 = gelu_e(acc1[mt][0]), g1 = gelu_e(acc1[mt][1]);
                float g2 = gelu_e(acc1[mt][2]), g3 = gelu_e(acc1[mt][3]);
                unsigned p0, p1;
                asm("v_cvt_pk_bf16_f32 %0, %1, %2" : "=v"(p0) : "v"(g0), "v"(g1));
                asm("v_cvt_pk_bf16_f32 %0, %1, %2" : "=v"(p1) : "v"(g2), "v"(g3));
                int tok = wm * 32 + mt * 16 + lm;
                int slot = (wn * 2 + (q >> 1)) ^ (tok & 7);
                u32x2 pk; pk[0] = p0; pk[1] = p1;
                *(u32x2*)(Gs + tok * 64 + slot * 8 + (q & 1) * 4) = pk;
            }
        }
        __syncthreads();   // Gs visible; all W1s(c) reads done -> W1s free

        // ---- stage W1(c+1) -> W1s, W2(c+1) -> buf[nb] (lands by next bar) ----
        if (c + 1 < 16) {
#pragma unroll
            for (int i = 0; i < 4; ++i)
                cp16(w1p + (size_t)(i * 16) * 256, w1d + (i * 16) * 32);
            u16* d = nb ? w2d1 : w2d0;
#pragma unroll
            for (int i = 0; i < 2; ++i)
                cp16(w2p + (size_t)(i * 16) * 1024, d + (i * 16) * 32);
        }
        w1p += 16384; w2p += 64;

        // ---- ffn2(c): Gs + W2s[cb] -> acc2 ----
        {
            const u16* W2c = W2s + cb * 8192;
            __builtin_amdgcn_s_setprio(1);
#pragma unroll
            for (int ks = 0; ks < 2; ++ks) {
                bf16x8 pa[2], wf[2];
#pragma unroll
                for (int mt = 0; mt < 2; ++mt) {
                    int tok = wm * 32 + mt * 16 + lm;
                    pa[mt] = *(const bf16x8*)(Gs + tok * 64 + (((ks * 4 + q) ^ (tok & 7)) * 8));
                }
#pragma unroll
                for (int nt = 0; nt < 2; ++nt)
                    wf[nt] = *(const bf16x8*)(W2c + (ks * 128 + wn * 32 + nt * 16 + lm) * 32 + q * 8);
#pragma unroll
                for (int mt = 0; mt < 2; ++mt)
#pragma unroll
                    for (int nt = 0; nt < 2; ++nt)
                        acc2[mt][nt] = __builtin_amdgcn_mfma_f32_16x16x32_bf16(
                            pa[mt], wf[nt], acc2[mt][nt], 0, 0, 0);
            }
            __builtin_amdgcn_s_setprio(0);
        }
        __syncthreads();   // drains vmcnt (W(c+1) landed); Gs reads done
    }

    // ---- LN + residual epilogue (stats exchange overlaid on Gs) ----
    float* stats = (float*)Gs;                   // [64][8] = 2KB
#pragma unroll
    for (int mt = 0; mt < 2; ++mt)
#pragma unroll
        for (int r = 0; r < 4; ++r) {
            float s1 = 0.f, s2 = 0.f;
#pragma unroll
            for (int nt = 0; nt < 2; ++nt) {
                float v = acc2[mt][nt][r];
                s1 += v; s2 += v * v;
            }
            s1 += __shfl_xor(s1, 1); s2 += __shfl_xor(s2, 1);
            s1 += __shfl_xor(s1, 2); s2 += __shfl_xor(s2, 2);
            s1 += __shfl_xor(s1, 4); s2 += __shfl_xor(s2, 4);
            s1 += __shfl_xor(s1, 8); s2 += __shfl_xor(s2, 8);
            if (lm == 0) {
                int row = wm * 32 + mt * 16 + q * 4 + r;
                stats[row * 8 + wn * 2] = s1;
                stats[row * 8 + wn * 2 + 1] = s2;
            }
        }
    __syncthreads();

    float gv[2], bv[2];
#pragma unroll
    for (int nt = 0; nt < 2; ++nt) {
        int col = wn * 32 + nt * 16 + lm;
        gv[nt] = g[col]; bv[nt] = bb[col];
    }
#pragma unroll
    for (int mt = 0; mt < 2; ++mt)
#pragma unroll
        for (int r = 0; r < 4; ++r) {
            int row = wm * 32 + mt * 16 + q * 4 + r;
            f32x4 st0 = *(const f32x4*)(stats + row * 8);
            f32x4 st1 = *(const f32x4*)(stats + row * 8 + 4);
            float s1 = st0[0] + st0[2] + st1[0] + st1[2];
            float s2 = st0[1] + st0[3] + st1[1] + st1[3];
            float mean = s1 * (1.f / 128.f);
            float var = fmaxf(s2 * (1.f / 128.f) - mean * mean, 0.f);
            float rs = rsqrtf(var + 1e-5f);
#pragma unroll
            for (int nt = 0; nt < 2; ++nt) {
                int col = wn * 32 + nt * 16 + lm;
                size_t gi = (size_t)(m0 + row) * 128 + col;
                outv[gi] = (acc2[mt][nt][r] - mean) * rs * gv[nt] + bv[nt] + resid[gi];
            }
        }
}

// ---------------------------------------------------------------------------
// Prep R13: LDS-tiled weight transposes (coalesced reads AND writes;
// conflict-free [64][65] tile) + fp32->bf16 act cast.
// Tiles: bx 0..15 Wq..Wm (4x4), 16..79 W1 (4x16), 80..111 W2 (16x2).
// ---------------------------------------------------------------------------
__global__ void prep_all(const float* __restrict__ Wq, const float* __restrict__ Wk,
                         const float* __restrict__ Wv, const float* __restrict__ Wm,
                         const float* __restrict__ W1, const float* __restrict__ W2,
                         const float* __restrict__ src, const float* __restrict__ tgt,
                         u16* __restrict__ ws, u16* __restrict__ srcb,
                         u16* __restrict__ tgtb)
{
    int bx = blockIdx.x;
    if (bx < 112) {
        __shared__ float T[64][65];
        const int t = threadIdx.x;
        const float* sp; u16* dst; int R, C, r0, c0;
        if (bx < 16) {                    // Wq,Wk,Wv,Wm: 128x128
            int m = bx >> 2, tt = bx & 3;
            sp = (m == 0) ? Wq : (m == 1) ? Wk : (m == 2) ? Wv : Wm;
            R = 128; C = 128; r0 = (tt >> 1) * 64; c0 = (tt & 1) * 64;
            dst = ws + m * 16384;
        } else if (bx < 80) {             // W1: 256x1024 -> W1T [1024][256]
            int tt = bx - 16;
            sp = W1; R = 256; C = 1024;
            r0 = (tt >> 4) * 64; c0 = (tt & 15) * 64;
            dst = ws + 65536;
        } else {                          // W2: 1024x128 -> W2T [128][1024]
            int tt = bx - 80;
            sp = W2; R = 1024; C = 128;
            r0 = (tt >> 1) * 64; c0 = (tt & 1) * 64;
            dst = ws + 327680;
        }
#pragma unroll
        for (int i = 0; i < 16; ++i) {    // coalesced fp32 read
            int idx = i * 256 + t, r = idx >> 6, c = idx & 63;
            T[r][c] = sp[(size_t)(r0 + r) * C + c0 + c];
        }
        __syncthreads();
#pragma unroll
        for (int i = 0; i < 16; ++i) {    // transposed LDS read, coalesced bf16 write
            int idx = i * 256 + t, n = idx >> 6, k = idx & 63;
            dst[(size_t)(c0 + n) * R + r0 + k] = f2b(T[k][n]);
        }
    } else {
        int idx = (bx - 112) * 256 + threadIdx.x;    // 0..2097151
        const float* s; u16* d; int i;
        if (idx < 1048576) { s = src; d = srcb; i = idx * 4; }
        else               { s = tgt; d = tgtb; i = (idx - 1048576) * 4; }
        f32x4 v = *(const f32x4*)(s + i);
        u16x4 o; o[0] = f2b(v[0]); o[1] = f2b(v[1]); o[2] = f2b(v[2]); o[3] = f2b(v[3]);
        *(u16x4*)(d + i) = o;
    }
}

// ---------------------------------------------------------------------------
// Workspace layout (u16 element offsets)
// ---------------------------------------------------------------------------
#define OFF_WQT  0u            // concat [WqT;WkT;WvT] 3x(128x128)
#define OFF_WMT  49152u
#define OFF_W1T  65536u
#define OFF_W2T  327680u
#define OFF_SRCB 458752u
#define OFF_TGTB 4653056u
#define OFF_QW   8847360u
#define OFF_KW   13041664u
#define OFF_VWT  17235968u
#define OFF_MSGB 21430272u     // bf16 msg, source-order; ends 25624576

extern "C" void kernel_launch(void* const* d_in, const int* in_sizes, int n_in,
                              void* d_out, int out_size, void* d_ws, size_t ws_size,
                              hipStream_t stream)
{
    (void)in_sizes; (void)n_in; (void)out_size; (void)ws_size;
    const float* source = (const float*)d_in[0];
    const float* target = (const float*)d_in[1];
    const float* Wq = (const float*)d_in[2];
    const float* Wk = (const float*)d_in[3];
    const float* Wv = (const float*)d_in[4];
    const float* Wm = (const float*)d_in[5];
    const float* g1 = (const float*)d_in[6];
    const float* b1 = (const float*)d_in[7];
    const float* W1 = (const float*)d_in[8];
    const float* W2 = (const float*)d_in[9];
    const float* g2 = (const float*)d_in[10];
    const float* b2 = (const float*)d_in[11];
    u16* ws = (u16*)d_ws;
    float* out = (float*)d_out;

    prep_all<<<8304, 256, 0, stream>>>(Wq, Wk, Wv, Wm, W1, W2, source, target,
                                       ws, ws + OFF_SRCB, ws + OFF_TGTB);
    gemm_qkv<<<dim3(256, 3), 256, 0, stream>>>(
        ws + OFF_SRCB, ws + OFF_TGTB, ws + OFF_WQT,
        ws + OFF_QW, ws + OFF_KW, ws + OFF_VWT);
    attn_msg<<<512, 256, 0, stream>>>(
        ws + OFF_QW, ws + OFF_KW, ws + OFF_VWT, ws + OFF_WMT, g1, b1,
        ws + OFF_MSGB);
    fused_ffn<<<512, 512, 0, stream>>>(
        ws + OFF_SRCB, ws + OFF_MSGB, ws + OFF_W1T, ws + OFF_W2T,
        g2, b2, source, out);
}